// Round 6
// baseline (111.442 us; speedup 1.0000x reference)
//
#include <hip/hip_runtime.h>

#define BATCH 262144
#define NITER 5

typedef __attribute__((ext_vector_type(4))) float f32x4;
typedef __attribute__((ext_vector_type(8))) short bf16x8;   // A/B frag, 16x16x32 bf16
typedef __attribute__((ext_vector_type(4))) short bf16x4;   // A/B frag, 16x16x16 bf16

// fp32 -> bf16, round-to-nearest-even (inputs finite; no NaN handling needed)
static __device__ __forceinline__ unsigned short f2bf(float f) {
    unsigned int u = __float_as_uint(f);
    u += 0x7fffu + ((u >> 16) & 1u);
    return (unsigned short)(u >> 16);
}

// R6: TLP boost. R5 ran 1024 blocks (4 waves/SIMD device-wide) with 4 serial
// dependent chunks per wave -> ~1.3k cyc of exposed per-wave latency that 4
// waves/SIMD can't hide (kernel ~25us vs 13us HBM floor, HBM only 50% of
// achievable). Now: 2 chunks/wave, 2048 blocks (8 waves/SIMD demand),
// launch_bounds(256,4) caps VGPR at 128 (est. use ~80, no spill).
// Jacobi 6->5 iters: contraction <=~0.3 => tail <=2e-4, invisible under the
// measured bf16-rounding-dominated absmax 1.95e-3 (threshold 8.55e-3).
__launch_bounds__(256, 4)
__global__ void clefo_mfma(const float* __restrict__ X,
                           const float* __restrict__ Z,
                           const float* __restrict__ Ups,
                           const float* __restrict__ Bm,
                           const float* __restrict__ Th,
                           const float* __restrict__ Gm,
                           const float* __restrict__ Lm,
                           float* __restrict__ Y) {
    const int tid  = threadIdx.x;
    const int lane = tid & 63;
    const int wave = tid >> 6;
    const int ln16 = lane & 15;   // n (batch-in-tile); also m for A-frags
    const int quad = lane >> 4;   // 0..3

    // --- A-fragments direct from global (one-time per wave; identical
    // addresses every wave -> L1 broadcast after first touch) ---
    const int woff = ln16 * 32 + quad * 8;
    union { float4 v[2]; float f[8]; } rb, rt, rl;
    rb.v[0] = *(const float4*)(Bm + woff); rb.v[1] = *(const float4*)(Bm + woff + 4);
    rt.v[0] = *(const float4*)(Th + woff); rt.v[1] = *(const float4*)(Th + woff + 4);
    rl.v[0] = *(const float4*)(Lm + woff); rl.v[1] = *(const float4*)(Lm + woff + 4);
    union { float4 v; float f[4]; } rg;
    rg.v = *(const float4*)(Gm + ln16 * 16 + quad * 4);

    union { bf16x8 v; unsigned short u[8]; } fB, fT, fL;
    #pragma unroll
    for (int j = 0; j < 8; ++j) {
        fB.u[j] = f2bf(rb.f[j]);
        fT.u[j] = f2bf(rt.f[j]);
        fL.u[j] = f2bf(rl.f[j]);
    }
    union { bf16x4 v; unsigned short u[4]; } fG;
    #pragma unroll
    for (int j = 0; j < 4; ++j) {
        const int k = quad * 4 + j;
        fG.u[j] = (k == ln16) ? (unsigned short)0 : f2bf(rg.f[j]);  // diag removed
    }

    const float4 uq = *(const float4*)(Ups + quad * 4);
    f32x4 bU = {uq.x, uq.y, uq.z, uq.w};
    f32x4 bC;
    #pragma unroll
    for (int r = 0; r < 4; ++r) {
        const int i = quad * 4 + r;
        bC[r] = 1.0f + 1e-7f - Gm[i * 16 + i];
    }

    const int base = blockIdx.x * 128 + wave * 32;   // 2 chunks of 16 per wave

    #pragma unroll
    for (int c = 0; c < 2; ++c) {
        const int b = base + c * 16 + ln16;
        // B-frag: lane (n=b%16, quad) holds v[k=quad*8+j][b] = X[b][quad*8+j].
        const float4* xp = (const float4*)(X + (size_t)b * 32) + quad * 2;
        const float4* zp = (const float4*)(Z + (size_t)b * 32) + quad * 2;
        const float4 x0 = xp[0], x1 = xp[1];
        const float4 z0 = zp[0], z1 = zp[1];

        union { bf16x8 v; unsigned short u[8]; } xf, zf;
        xf.u[0] = f2bf(x0.x); xf.u[1] = f2bf(x0.y); xf.u[2] = f2bf(x0.z); xf.u[3] = f2bf(x0.w);
        xf.u[4] = f2bf(x1.x); xf.u[5] = f2bf(x1.y); xf.u[6] = f2bf(x1.z); xf.u[7] = f2bf(x1.w);
        zf.u[0] = f2bf(z0.x); zf.u[1] = f2bf(z0.y); zf.u[2] = f2bf(z0.z); zf.u[3] = f2bf(z0.w);
        zf.u[4] = f2bf(z1.x); zf.u[5] = f2bf(z1.y); zf.u[6] = f2bf(z1.z); zf.u[7] = f2bf(z1.w);

        // rhs = Ups + B@x + Theta@z ; d = Lam@x   (fp32 accumulate)
        f32x4 rhs = __builtin_amdgcn_mfma_f32_16x16x32_bf16(fB.v, xf.v, bU, 0, 0, 0);
        rhs = __builtin_amdgcn_mfma_f32_16x16x32_bf16(fT.v, zf.v, rhs, 0, 0, 0);
        const f32x4 zero = {0.f, 0.f, 0.f, 0.f};
        const f32x4 d = __builtin_amdgcn_mfma_f32_16x16x32_bf16(fL.v, xf.v, zero, 0, 0, 0);

        // Jacobi: inv_i = 1/(1+eps-G_ii-d_i); y <- inv*(rhs + Goff@y).
        f32x4 inv, y;
        #pragma unroll
        for (int r = 0; r < 4; ++r) {
            inv[r] = __builtin_amdgcn_rcpf(bC[r] - d[r]);
            y[r] = rhs[r] * inv[r];
        }
        #pragma unroll
        for (int it = 0; it < NITER; ++it) {
            union { bf16x4 v; unsigned short u[4]; } yb;
            yb.u[0] = f2bf(y[0]); yb.u[1] = f2bf(y[1]);
            yb.u[2] = f2bf(y[2]); yb.u[3] = f2bf(y[3]);
            const f32x4 t = __builtin_amdgcn_mfma_f32_16x16x16bf16_1k(fG.v, yb.v, rhs, 0, 0, 0);
            y = t * inv;
        }

        // D layout: lane (b, quad) holds Y[b][quad*4 .. quad*4+3]; a wave
        // writes one contiguous 1KB region.
        *(float4*)(Y + (size_t)b * 16 + quad * 4) = make_float4(y[0], y[1], y[2], y[3]);
    }
}

extern "C" void kernel_launch(void* const* d_in, const int* in_sizes, int n_in,
                              void* d_out, int out_size, void* d_ws, size_t ws_size,
                              hipStream_t stream) {
    const float* X     = (const float*)d_in[0];
    const float* Z     = (const float*)d_in[1];
    const float* Ups   = (const float*)d_in[2];
    const float* Bmat  = (const float*)d_in[3];
    const float* Theta = (const float*)d_in[4];
    const float* Gamma = (const float*)d_in[5];
    const float* Lam   = (const float*)d_in[6];
    float* Y = (float*)d_out;

    clefo_mfma<<<BATCH / 128, 256, 0, stream>>>(X, Z, Ups, Bmat, Theta, Gamma, Lam, Y);
}